// Round 2
// baseline (16158.656 us; speedup 1.0000x reference)
//
#include <hip/hip_runtime.h>
#include <hip/hip_bf16.h>

// LSTM: S=512, B=128, I=256, H=512. Gates stacked (f,i,o,c) along dim0 of W/U.
// Device tensors are FP32 (per reference dtypes); MFMA compute in bf16.
//
// Persistent cooperative kernel:
//   - 4 batch-groups x 32 rows; 64 WGs per group (8 H-cols each => 32 gate-cols).
//   - W/U rows converted to bf16 and staged once to LDS (XOR-swizzled).
//   - c-state in registers; h double-buffered (bf16 in ws for Tier A).
//   - One group-local release/acquire barrier per timestep.

#define S_LEN 512
#define BATCH 128
#define ISZ   256
#define HSZ   512

typedef __attribute__((ext_vector_type(8))) short  s16x8;
typedef __attribute__((ext_vector_type(4))) float  f32x4;

#define XOFF 4096                                   // bf16 x starts here in ws
#define XBYTES ((size_t)S_LEN * BATCH * ISZ * 2)    // 33,554,432
#define HOFF (XOFF + XBYTES)                        // bf16 h ping-pong
#define HBYTES ((size_t)2 * BATCH * HSZ * 2)        // 262,144
#define WS_NEED (HOFF + HBYTES)

__device__ __forceinline__ unsigned short f2bf(float f) {
    unsigned u = __float_as_uint(f);
    u += 0x7fffu + ((u >> 16) & 1u);                // round-to-nearest-even
    return (unsigned short)(u >> 16);
}

__device__ __forceinline__ s16x8 ld8f_bf(const float* p) {
    f32x4 a = *(const f32x4*)p;
    f32x4 b = *(const f32x4*)(p + 4);
    s16x8 r;
    r[0] = (short)f2bf(a[0]); r[1] = (short)f2bf(a[1]);
    r[2] = (short)f2bf(a[2]); r[3] = (short)f2bf(a[3]);
    r[4] = (short)f2bf(b[0]); r[5] = (short)f2bf(b[1]);
    r[6] = (short)f2bf(b[2]); r[7] = (short)f2bf(b[3]);
    return r;
}

__global__ void __launch_bounds__(256, 1)
cvt_x_kernel(const float* __restrict__ x, unsigned short* __restrict__ xbf, int n8) {
    int i = blockIdx.x * blockDim.x + threadIdx.x;
    const int stride = gridDim.x * blockDim.x;
    for (; i < n8; i += stride)
        *(s16x8*)(xbf + (size_t)i * 8) = ld8f_bf(x + (size_t)i * 8);
}

template <bool BIGWS>
__global__ void __launch_bounds__(256, 1)
lstm_persistent(const float* __restrict__ x,
                const float* __restrict__ W,
                const float* __restrict__ bW,
                const float* __restrict__ U,
                const float* __restrict__ bU,
                float* __restrict__ out,
                unsigned char* __restrict__ ws)
{
    __shared__ unsigned short U_lds[32 * 512];      // 32 KiB
    __shared__ unsigned short W_lds[32 * 256];      // 16 KiB
    __shared__ float g_lds[32][33];                 // 4.2 KiB (+1 pad)

    const int tid  = threadIdx.x;
    const int bid  = blockIdx.x;
    const int grp  = bid >> 6;                      // 4 groups of 32 batch rows
    const int wg   = bid & 63;                      // 64 WGs per group
    const int jBase = wg * 8;                       // H-col base for this WG
    const int rBase = grp * 32;                     // batch-row base

    unsigned int*   ctr = (unsigned int*)(ws + (size_t)grp * 128);
    unsigned short* h0  = (unsigned short*)(ws + HOFF);
    unsigned short* h1  = h0 + BATCH * HSZ;
    unsigned short* hbuf[2] = { h0, h1 };
    const unsigned short* xbf = (const unsigned short*)(ws + XOFF);

    // ---- stage this WG's 32 weight rows (fp32 -> bf16) into swizzled LDS ----
    {
        const int n  = tid >> 3;                    // local gate-col 0..31
        const int q  = tid & 7;                     // chunk within row
        const int gt = n >> 3, jj = n & 7;
        const int gRow = gt * HSZ + jBase + jj;
        const int swz  = (n & 7) << 4;
        const float* up = U + (size_t)gRow * HSZ + q * 64;
        char* ud = (char*)U_lds + n * 1024;
        #pragma unroll
        for (int i = 0; i < 8; ++i)
            *(s16x8*)(ud + ((q * 128 + i * 16) ^ swz)) = ld8f_bf(up + i * 8);
        const float* wp = W + (size_t)gRow * ISZ + q * 32;
        char* wd = (char*)W_lds + n * 512;
        #pragma unroll
        for (int i = 0; i < 4; ++i)
            *(s16x8*)(wd + ((q * 64 + i * 16) ^ swz)) = ld8f_bf(wp + i * 8);
    }

    // ---- per-wave MFMA geometry: 4 waves = 2x2 quadrants of the 32x32 tile ----
    const int w    = tid >> 6;
    const int lane = tid & 63;
    const int l15  = lane & 15;
    const int lq   = lane >> 4;                     // k-group 0..3
    const int mq   = w >> 1, nq = w & 1;
    const int ncol = nq * 16 + l15;                 // WG-local gate-col 0..31
    const int gt_w = ncol >> 3, jj_w = ncol & 7;
    const int gRow_w = gt_w * HSZ + jBase + jj_w;
    const float bias = bW[gRow_w] + bU[gRow_w];
    const int arow = rBase + mq * 16 + l15;         // batch row for A-fragments
    const int bswz = (ncol & 7) << 4;
    const char* uld = (const char*)U_lds + ncol * 1024;
    const char* wld = (const char*)W_lds + ncol * 512;

    // ---- epilogue mapping: one (row, H-col) pair per thread; c in register ----
    const int eb   = tid >> 3;                      // local batch row 0..31
    const int ejj  = tid & 7;                       // local H-col 0..7
    const int orow = rBase + eb;
    const int ocol = jBase + ejj;
    float c_reg = 0.f;

    __syncthreads();

    for (int t = 0; t < S_LEN; ++t) {
        if (t > 0) {
            if (tid == 0) {
                const unsigned target = 64u * (unsigned)t;
                while (__hip_atomic_load(ctr, __ATOMIC_ACQUIRE,
                                         __HIP_MEMORY_SCOPE_AGENT) < target)
                    __builtin_amdgcn_s_sleep(2);
            }
            __syncthreads();
        }

        f32x4 acc = { bias, bias, bias, bias };
        // fused x @ W^T (K = 256)
        #pragma unroll
        for (int ki = 0; ki < 8; ++ki) {
            s16x8 a;
            if constexpr (BIGWS)
                a = *(const s16x8*)(xbf + ((size_t)t * BATCH + arow) * ISZ + lq * 8 + ki * 32);
            else
                a = ld8f_bf(x + ((size_t)t * BATCH + arow) * ISZ + lq * 8 + ki * 32);
            s16x8 b = *(const s16x8*)(wld + ((ki * 64 + lq * 16) ^ bswz));
            acc = __builtin_amdgcn_mfma_f32_16x16x32_bf16(a, b, acc, 0, 0, 0);
        }
        // h @ U^T (K = 512); h == 0 at t == 0
        if (t > 0) {
            f32x4 acc2 = { 0.f, 0.f, 0.f, 0.f };
            #pragma unroll
            for (int ki = 0; ki < 16; ++ki) {
                s16x8 a;
                if constexpr (BIGWS)
                    a = *(const s16x8*)(hbuf[(t - 1) & 1] + (size_t)arow * HSZ + lq * 8 + ki * 32);
                else
                    a = ld8f_bf(out + ((size_t)(t - 1) * BATCH + arow) * HSZ + lq * 8 + ki * 32);
                s16x8 b = *(const s16x8*)(uld + ((ki * 64 + lq * 16) ^ bswz));
                acc2 = __builtin_amdgcn_mfma_f32_16x16x32_bf16(a, b, acc2, 0, 0, 0);
            }
            acc += acc2;
        }

        #pragma unroll
        for (int r = 0; r < 4; ++r)
            g_lds[mq * 16 + lq * 4 + r][ncol] = acc[r];
        __syncthreads();

        // gate nonlinearities + state update (per-thread, fp32)
        const float gf = g_lds[eb][ejj];
        const float gi = g_lds[eb][ejj + 8];
        const float go = g_lds[eb][ejj + 16];
        const float gc = g_lds[eb][ejj + 24];

        const float fg = 1.f / (1.f + __expf(-gf));
        const float ig = 1.f / (1.f + __expf(-gi));
        const float og = 1.f / (1.f + __expf(-go));
        const float ec = __expf(-2.f * fabsf(gc));
        const float cd = copysignf((1.f - ec) / (1.f + ec), gc);

        c_reg = fg * c_reg + ig * cd;

        const float eh = __expf(-2.f * fabsf(c_reg));
        const float th = copysignf((1.f - eh) / (1.f + eh), c_reg);
        const float hn = og * th;

        out[((size_t)t * BATCH + orow) * HSZ + ocol] = hn;                  // h_seq (fp32)
        if constexpr (BIGWS)
            hbuf[t & 1][(size_t)orow * HSZ + ocol] = f2bf(hn);              // next-step h (bf16)
        if (t == S_LEN - 1) {
            const size_t HSEQ = (size_t)S_LEN * BATCH * HSZ;
            out[HSEQ + (size_t)orow * HSZ + ocol] = hn;                     // h_final
            out[HSEQ + (size_t)BATCH * HSZ + (size_t)orow * HSZ + ocol] = c_reg; // c_final
        }

        if (t < S_LEN - 1) {
            __threadfence();                        // make h writes agent-visible
            __syncthreads();                        // all threads' stores fenced
            if (tid == 0)
                __hip_atomic_fetch_add(ctr, 1u, __ATOMIC_RELEASE,
                                       __HIP_MEMORY_SCOPE_AGENT);
        }
    }
}

extern "C" void kernel_launch(void* const* d_in, const int* in_sizes, int n_in,
                              void* d_out, int out_size, void* d_ws, size_t ws_size,
                              hipStream_t stream) {
    const float* x  = (const float*)d_in[0];
    const float* W  = (const float*)d_in[1];
    const float* bW = (const float*)d_in[2];
    const float* U  = (const float*)d_in[3];
    const float* bU = (const float*)d_in[4];
    float* out = (float*)d_out;
    unsigned char* ws = (unsigned char*)d_ws;

    // zero the per-group barrier counters (ws is NOT re-poisoned between replays)
    hipMemsetAsync(ws, 0, 4096, stream);

    void* args[] = { (void*)&x, (void*)&W, (void*)&bW, (void*)&U, (void*)&bU,
                     (void*)&out, (void*)&ws };

    if (ws_size >= WS_NEED) {
        const int n8 = S_LEN * BATCH * ISZ / 8;
        cvt_x_kernel<<<2048, 256, 0, stream>>>(x, (unsigned short*)(ws + XOFF), n8);
        hipLaunchCooperativeKernel((void*)lstm_persistent<true>, dim3(256), dim3(256),
                                   args, 0, stream);
    } else {
        hipLaunchCooperativeKernel((void*)lstm_persistent<false>, dim3(256), dim3(256),
                                   args, 0, stream);
    }
}

// Round 3
// 2331.859 us; speedup vs baseline: 6.9295x; 6.9295x over previous
//
#include <hip/hip_runtime.h>
#include <hip/hip_bf16.h>

// LSTM: S=512, B=128, I=256, H=512. Gates stacked (f,i,o,c) along dim0 of W/U.
// FP32 tensors; MFMA in bf16; epilogue/state fp32.
//
// Persistent cooperative kernel, 256 WGs x 256 thr:
//   - 4 independent batch-groups x 32 rows; 64 WGs/group (8 H-cols each).
//   - Weight B-fragments held in REGISTERS (ub[16]+wb[8]) for all 512 steps.
//   - h exchanged between WGs via Infinity-Cache (sc0 sc1 loads/stores) --
//     no agent fences, no buffer_inv/buffer_wbl2 in the hot loop.
//   - One group-local flag (relaxed agent atomicAdd / relaxed sc0sc1 poll) per step.

#define S_LEN 512
#define BATCH 128
#define ISZ   256
#define HSZ   512

typedef __attribute__((ext_vector_type(8))) short  s16x8;
typedef __attribute__((ext_vector_type(4))) float  f32x4;
typedef __attribute__((ext_vector_type(2))) float  f32x2;

#define XOFF 4096                                   // bf16 x in ws (Tier A)
#define XBYTES ((size_t)S_LEN * BATCH * ISZ * 2)    // 32 MiB
#define HOFF (XOFF + XBYTES)
#define HBYTES ((size_t)2 * BATCH * HSZ * 2)        // 256 KiB
#define WS_NEED (HOFF + HBYTES)
#define HOFF_SMALL 4096                             // Tier B: h right after ctrs

__device__ __forceinline__ unsigned short f2bf(float f) {
    unsigned u = __float_as_uint(f);
    u += 0x7fffu + ((u >> 16) & 1u);                // RNE
    return (unsigned short)(u >> 16);
}

__device__ __forceinline__ s16x8 ld8f_bf(const float* p) {
    f32x4 a = *(const f32x4*)p;
    f32x4 b = *(const f32x4*)(p + 4);
    s16x8 r;
    r[0] = (short)f2bf(a[0]); r[1] = (short)f2bf(a[1]);
    r[2] = (short)f2bf(a[2]); r[3] = (short)f2bf(a[3]);
    r[4] = (short)f2bf(b[0]); r[5] = (short)f2bf(b[1]);
    r[6] = (short)f2bf(b[2]); r[7] = (short)f2bf(b[3]);
    return r;
}

__global__ void __launch_bounds__(256, 1)
cvt_x_kernel(const float* __restrict__ x, unsigned short* __restrict__ xbf, int n8) {
    int i = blockIdx.x * blockDim.x + threadIdx.x;
    const int stride = gridDim.x * blockDim.x;
    for (; i < n8; i += stride)
        *(s16x8*)(xbf + (size_t)i * 8) = ld8f_bf(x + (size_t)i * 8);
}

#define MFMA_BF16 __builtin_amdgcn_mfma_f32_16x16x32_bf16

template <bool BIGWS>
__global__ void __launch_bounds__(256, 1)
lstm_fast(const float* __restrict__ x,
          const float* __restrict__ W,
          const float* __restrict__ bW,
          const float* __restrict__ U,
          const float* __restrict__ bU,
          float* __restrict__ out,
          unsigned char* __restrict__ ws)
{
    __shared__ float g_lds[32][33];                 // gate-tile exchange (+1 pad)

    const int tid  = threadIdx.x;
    const int bid  = blockIdx.x;
    const int grp  = bid >> 6;                      // 4 groups of 32 batch rows
    const int wg   = bid & 63;
    const int jBase = wg * 8;                       // H-col base
    const int rBase = grp * 32;                     // batch-row base

    unsigned* ctr = (unsigned*)(ws + (size_t)grp * 128);
    unsigned short* hb = (unsigned short*)(ws + (BIGWS ? HOFF : HOFF_SMALL));
    unsigned short* h0 = hb;
    unsigned short* h1 = hb + BATCH * HSZ;
    const unsigned short* xbf = (const unsigned short*)(ws + XOFF);

    // ---- wave geometry: 4 waves = 2x2 quadrants of the 32-row x 32-gate-col tile ----
    const int w    = tid >> 6;
    const int lane = tid & 63;
    const int l15  = lane & 15;
    const int lq   = lane >> 4;                     // k-group 0..3
    const int mq   = w >> 1, nq = w & 1;
    const int ncol = nq * 16 + l15;                 // WG-local gate-col 0..31
    const int gRow = (ncol >> 3) * HSZ + jBase + (ncol & 7);
    const float bias = bW[gRow] + bU[gRow];
    const int arow = rBase + mq * 16 + l15;         // batch row for A fragments

    // ---- step-invariant B fragments: straight from global fp32 -> bf16 regs ----
    s16x8 ub[16], wb[8];
    #pragma unroll
    for (int ki = 0; ki < 16; ++ki)
        ub[ki] = ld8f_bf(U + (size_t)gRow * HSZ + ki * 32 + lq * 8);
    #pragma unroll
    for (int ki = 0; ki < 8; ++ki)
        wb[ki] = ld8f_bf(W + (size_t)gRow * ISZ + ki * 32 + lq * 8);

    // ---- epilogue mapping: 128 threads x (1 row, 2 cols); c-state in regs ----
    const int er   = tid >> 2;                      // local row 0..31 (tid<128)
    const int ej0  = (tid & 3) * 2;                 // col pair 0,2,4,6
    const int orow = rBase + er;
    const int ocol = jBase + ej0;
    float c0 = 0.f, c1 = 0.f;

    for (int t = 0; t < S_LEN; ++t) {
        f32x4 acc  = { bias, bias, bias, bias };
        f32x4 acc2 = { 0.f, 0.f, 0.f, 0.f };

        // x @ W^T (K=256) -- no cross-WG dependency; overlaps producers' tail
        #pragma unroll
        for (int ki = 0; ki < 8; ++ki) {
            s16x8 a;
            if constexpr (BIGWS)
                a = *(const s16x8*)(xbf + ((size_t)t * BATCH + arow) * ISZ + lq * 8 + ki * 32);
            else
                a = ld8f_bf(x + ((size_t)t * BATCH + arow) * ISZ + lq * 8 + ki * 32);
            if (ki & 1) acc2 = MFMA_BF16(a, wb[ki], acc2, 0, 0, 0);
            else        acc  = MFMA_BF16(a, wb[ki], acc,  0, 0, 0);
        }

        if (t > 0) {
            // wait for all 64 WGs of this group to have published h_{t-1}
            const unsigned target = 64u * (unsigned)t;
            for (;;) {
                unsigned v;
                asm volatile("global_load_dword %0, %1, off sc0 sc1\n\t"
                             "s_waitcnt vmcnt(0)"
                             : "=v"(v) : "v"(ctr) : "memory");
                if (v >= target) break;
                __builtin_amdgcn_s_sleep(2);
            }

            const unsigned short* hp = ((t & 1) ? h0 : h1) + (size_t)arow * HSZ + lq * 8;
            s16x8 f0,f1,f2,f3,f4,f5,f6,f7,f8,f9,f10,f11,f12,f13,f14,f15;
#define LDH(d, o) asm volatile("global_load_dwordx4 %0, %1, off offset:" o " sc0 sc1" \
                               : "=v"(d) : "v"(hp) : "memory")
            LDH(f0,"0");    LDH(f1,"64");   LDH(f2,"128");  LDH(f3,"192");
            LDH(f4,"256");  LDH(f5,"320");  LDH(f6,"384");  LDH(f7,"448");
            LDH(f8,"512");  LDH(f9,"576");  LDH(f10,"640"); LDH(f11,"704");
            LDH(f12,"768"); LDH(f13,"832"); LDH(f14,"896"); LDH(f15,"960");
#undef LDH
            asm volatile("s_waitcnt vmcnt(0)" ::: "memory");
            __builtin_amdgcn_sched_barrier(0);      // keep MFMAs below the wait

            acc  = MFMA_BF16(f0,  ub[0],  acc,  0, 0, 0);
            acc2 = MFMA_BF16(f1,  ub[1],  acc2, 0, 0, 0);
            acc  = MFMA_BF16(f2,  ub[2],  acc,  0, 0, 0);
            acc2 = MFMA_BF16(f3,  ub[3],  acc2, 0, 0, 0);
            acc  = MFMA_BF16(f4,  ub[4],  acc,  0, 0, 0);
            acc2 = MFMA_BF16(f5,  ub[5],  acc2, 0, 0, 0);
            acc  = MFMA_BF16(f6,  ub[6],  acc,  0, 0, 0);
            acc2 = MFMA_BF16(f7,  ub[7],  acc2, 0, 0, 0);
            acc  = MFMA_BF16(f8,  ub[8],  acc,  0, 0, 0);
            acc2 = MFMA_BF16(f9,  ub[9],  acc2, 0, 0, 0);
            acc  = MFMA_BF16(f10, ub[10], acc,  0, 0, 0);
            acc2 = MFMA_BF16(f11, ub[11], acc2, 0, 0, 0);
            acc  = MFMA_BF16(f12, ub[12], acc,  0, 0, 0);
            acc2 = MFMA_BF16(f13, ub[13], acc2, 0, 0, 0);
            acc  = MFMA_BF16(f14, ub[14], acc,  0, 0, 0);
            acc2 = MFMA_BF16(f15, ub[15], acc2, 0, 0, 0);
        }

        #pragma unroll
        for (int r = 0; r < 4; ++r)
            g_lds[mq * 16 + lq * 4 + r][ncol] = acc[r] + acc2[r];
        __syncthreads();

        if (tid < 128) {
            const float gf0 = g_lds[er][ej0],      gf1 = g_lds[er][ej0 + 1];
            const float gi0 = g_lds[er][ej0 + 8],  gi1 = g_lds[er][ej0 + 9];
            const float go0 = g_lds[er][ej0 + 16], go1 = g_lds[er][ej0 + 17];
            const float gc0 = g_lds[er][ej0 + 24], gc1 = g_lds[er][ej0 + 25];

            const float fg0 = 1.f / (1.f + __expf(-gf0));
            const float fg1 = 1.f / (1.f + __expf(-gf1));
            const float ig0 = 1.f / (1.f + __expf(-gi0));
            const float ig1 = 1.f / (1.f + __expf(-gi1));
            const float og0 = 1.f / (1.f + __expf(-go0));
            const float og1 = 1.f / (1.f + __expf(-go1));
            const float e0 = __expf(-2.f * fabsf(gc0));
            const float e1 = __expf(-2.f * fabsf(gc1));
            const float cd0 = copysignf((1.f - e0) / (1.f + e0), gc0);
            const float cd1 = copysignf((1.f - e1) / (1.f + e1), gc1);

            c0 = fg0 * c0 + ig0 * cd0;
            c1 = fg1 * c1 + ig1 * cd1;

            const float t0 = __expf(-2.f * fabsf(c0));
            const float t1 = __expf(-2.f * fabsf(c1));
            const float hn0 = og0 * copysignf((1.f - t0) / (1.f + t0), c0);
            const float hn1 = og1 * copysignf((1.f - t1) / (1.f + t1), c1);

            f32x2 hv = { hn0, hn1 };
            *(f32x2*)(out + ((size_t)t * BATCH + orow) * HSZ + ocol) = hv;   // h_seq

            if (t < S_LEN - 1) {
                // publish h_t (bf16 pair) through the coherent point
                unsigned hwv = (unsigned)f2bf(hn0) | ((unsigned)f2bf(hn1) << 16);
                unsigned short* hd = ((t & 1) ? h1 : h0) + (size_t)orow * HSZ + ocol;
                asm volatile("global_store_dword %0, %1, off sc0 sc1"
                             :: "v"(hd), "v"(hwv) : "memory");
            } else {
                const size_t HSEQ = (size_t)S_LEN * BATCH * HSZ;
                *(f32x2*)(out + HSEQ + (size_t)orow * HSZ + ocol) = hv;      // h_final
                f32x2 cv = { c0, c1 };
                *(f32x2*)(out + HSEQ + (size_t)BATCH * HSZ
                          + (size_t)orow * HSZ + ocol) = cv;                 // c_final
            }
        }

        if (t < S_LEN - 1) {
            asm volatile("s_waitcnt vmcnt(0)" ::: "memory");   // h stores acked at IF$
            __syncthreads();                                   // whole WG done
            if (tid == 0)
                __hip_atomic_fetch_add(ctr, 1u, __ATOMIC_RELAXED,
                                       __HIP_MEMORY_SCOPE_AGENT);
        }
    }
}

extern "C" void kernel_launch(void* const* d_in, const int* in_sizes, int n_in,
                              void* d_out, int out_size, void* d_ws, size_t ws_size,
                              hipStream_t stream) {
    const float* x  = (const float*)d_in[0];
    const float* W  = (const float*)d_in[1];
    const float* bW = (const float*)d_in[2];
    const float* U  = (const float*)d_in[3];
    const float* bU = (const float*)d_in[4];
    float* out = (float*)d_out;
    unsigned char* ws = (unsigned char*)d_ws;

    // barrier counters must be 0 at every launch (ws is not re-poisoned)
    hipMemsetAsync(ws, 0, 4096, stream);

    void* args[] = { (void*)&x, (void*)&W, (void*)&bW, (void*)&U, (void*)&bU,
                     (void*)&out, (void*)&ws };

    if (ws_size >= WS_NEED) {
        const int n8 = S_LEN * BATCH * ISZ / 8;
        cvt_x_kernel<<<2048, 256, 0, stream>>>(x, (unsigned short*)(ws + XOFF), n8);
        hipLaunchCooperativeKernel((void*)lstm_fast<true>, dim3(256), dim3(256),
                                   args, 0, stream);
    } else {
        hipLaunchCooperativeKernel((void*)lstm_fast<false>, dim3(256), dim3(256),
                                   args, 0, stream);
    }
}